// Round 3
// baseline (241.959 us; speedup 1.0000x reference)
//
#include <hip/hip_runtime.h>

constexpr int Bn = 8, S = 2048, E = 1024, H = 64;
constexpr float SCALE = 0.03125f;     // E^-0.5 (folded into q)
constexpr float LOG2E = 1.44269504f;

typedef __attribute__((ext_vector_type(8))) short short8;  // 8 bf16
typedef __attribute__((ext_vector_type(4))) float f32x4;   // MFMA C/D

__device__ __forceinline__ unsigned short f2bf(float f) {
  unsigned u = __builtin_bit_cast(unsigned, f);
  u += 0x7fffu + ((u >> 16) & 1u);    // RNE
  return (unsigned short)(u >> 16);
}
__device__ __forceinline__ ushort4 f4bf(float4 f) {
  return make_ushort4(f2bf(f.x), f2bf(f.y), f2bf(f.z), f2bf(f.w));
}
__device__ __forceinline__ short8 pack8(float4 a, float4 b) {
  short8 r;
  r[0] = (short)f2bf(a.x); r[1] = (short)f2bf(a.y);
  r[2] = (short)f2bf(a.z); r[3] = (short)f2bf(a.w);
  r[4] = (short)f2bf(b.x); r[5] = (short)f2bf(b.y);
  r[6] = (short)f2bf(b.z); r[7] = (short)f2bf(b.w);
  return r;
}

// ---------- W [1024][64] fp32 -> WT3 [3][64][1024] bf16 ----------
__global__ __launch_bounds__(256) void wtrans_kernel(
    const float* __restrict__ Wq, const float* __restrict__ Wk,
    const float* __restrict__ Wv, unsigned short* __restrict__ WT3) {
  __shared__ unsigned short tb[64][72];
  const int m = blockIdx.x >> 4;            // 3 mats x 16 e-tiles
  const int e0 = (blockIdx.x & 15) * 64;
  const float* W = (m == 0) ? Wq : (m == 1) ? Wk : Wv;
  const int t = threadIdx.x;
#pragma unroll
  for (int it = 0; it < 4; ++it) {
    int idx = t + it * 256;
    int r = idx >> 4, c4 = idx & 15;
    float4 f = ((const float4*)(W + (long)(e0 + r) * H))[c4];
    *(ushort4*)&tb[r][c4 * 4] = f4bf(f);
  }
  __syncthreads();
#pragma unroll
  for (int it = 0; it < 4; ++it) {
    int idx = t + it * 256;
    int h = idx >> 4, e4 = idx & 15;
    ushort4 u = make_ushort4(tb[e4 * 4 + 0][h], tb[e4 * 4 + 1][h],
                             tb[e4 * 4 + 2][h], tb[e4 * 4 + 3][h]);
    ((ushort4*)(WT3 + (long)(m * 64 + h) * E + e0))[e4] = u;
  }
}

// ---------- QKV: no LDS, no barriers. A=x (fp32->bf16 in reg), B=WT3 (L2).
// Outputs: q bf16 [s][h] (pre-scaled), k bf16 [s][h], vT bf16 [b][h][s].
__global__ __launch_bounds__(128) void qkv_kernel(
    const float* __restrict__ x, const unsigned short* __restrict__ WT3,
    unsigned short* __restrict__ q, unsigned short* __restrict__ kk,
    unsigned short* __restrict__ vT) {
  const int t = threadIdx.x;
  const int w = t >> 6, lane = t & 63, l15 = lane & 15, g = lane >> 4;
  const long row0 = (long)blockIdx.x * 32 + w * 16;
  const float* xr = x + (row0 + l15) * E + g * 8;
  const unsigned short* wb = WT3 + (long)l15 * E + g * 8;

  f32x4 acc[3][4];
#pragma unroll
  for (int mm = 0; mm < 3; ++mm)
#pragma unroll
    for (int hc = 0; hc < 4; ++hc) acc[mm][hc] = f32x4{0.f, 0.f, 0.f, 0.f};

#pragma unroll 2
  for (int c = 0; c < 16; ++c) {
    short8 a[2];
#pragma unroll
    for (int kh = 0; kh < 2; ++kh) {
      const float* p = xr + c * 64 + kh * 32;
      float4 f0 = *(const float4*)p;
      float4 f1 = *(const float4*)(p + 4);
      a[kh] = pack8(f0, f1);
    }
#pragma unroll
    for (int mm = 0; mm < 3; ++mm)
#pragma unroll
      for (int hc = 0; hc < 4; ++hc)
#pragma unroll
        for (int kh = 0; kh < 2; ++kh) {
          short8 bfr = *(const short8*)(wb + (long)(mm * 64 + hc * 16) * E + c * 64 + kh * 32);
          acc[mm][hc] = __builtin_amdgcn_mfma_f32_16x16x32_bf16(a[kh], bfr, acc[mm][hc], 0, 0, 0);
        }
  }

  const int b = (int)(row0 >> 11);           // 32 | 2048: block within one batch
  const int sl = (int)(row0 & 2047) + g * 4;
#pragma unroll
  for (int hc = 0; hc < 4; ++hc) {
    const int col = hc * 16 + l15;
#pragma unroll
    for (int r = 0; r < 4; ++r) {
      long row = row0 + g * 4 + r;           // C/D: row=(lane>>4)*4+reg, col=lane&15
      q[row * H + col]  = f2bf(acc[0][hc][r] * SCALE);
      kk[row * H + col] = f2bf(acc[1][hc][r]);
    }
    ushort4 v4 = make_ushort4(f2bf(acc[2][hc][0]), f2bf(acc[2][hc][1]),
                              f2bf(acc[2][hc][2]), f2bf(acc[2][hc][3]));
    *(ushort4*)(vT + ((long)b * H + col) * S + sl) = v4;  // 4 consecutive s
  }
}

// ---------- causal flash attention, bf16 MFMA ----------
// Q-tile 32 (2 waves x 16 rows), K-tile 64, grid 512 (2 blocks/CU).
// Complementary pairing: blocks c and c+256 have qt summing to 63.
__global__ __launch_bounds__(128) void attn_kernel(
    const unsigned short* __restrict__ q, const unsigned short* __restrict__ k,
    const unsigned short* __restrict__ vT, float* __restrict__ out) {
  __shared__ unsigned short ks[64][72];   // [key][h]
  __shared__ unsigned short vt[64][72];   // [h][key]
  __shared__ unsigned short pl[32][72];   // [qrow][key]
  const int t = threadIdx.x;
  const int w = t >> 6, lane = t & 63, l15 = lane & 15, g = lane >> 4;
  const int jj = blockIdx.x >> 3, b = blockIdx.x & 7;
  const int qt = (jj < 32) ? jj : 95 - jj;   // jj & jj+32 sum to 63
  const unsigned short* qb = q + ((long)b * S + qt * 32 + w * 16 + l15) * H + g * 8;
  const unsigned short* kb = k + (long)b * S * H;
  const unsigned short* vb = vT + (long)b * H * S;

  short8 aq0 = *(const short8*)qb;          // A-frags direct from global
  short8 aq1 = *(const short8*)(qb + 32);

  f32x4 O[4];
  float m_[4], l_[4];
#pragma unroll
  for (int c = 0; c < 4; ++c) O[c] = f32x4{0.f, 0.f, 0.f, 0.f};
#pragma unroll
  for (int r = 0; r < 4; ++r) { m_[r] = -1e30f; l_[r] = 0.f; }

  const int kt_max = qt >> 1;
  short8 pk[4], pv[4];
#pragma unroll
  for (int it = 0; it < 4; ++it) {          // prologue: tile 0
    int idx = t + it * 128;
    int r = idx >> 3, c8 = idx & 7;
    pk[it] = *(const short8*)(kb + (long)r * H + c8 * 8);
    pv[it] = *(const short8*)(vb + (long)r * S + c8 * 8);
  }
#pragma unroll
  for (int it = 0; it < 4; ++it) {
    int idx = t + it * 128;
    int r = idx >> 3, c8 = idx & 7;
    *(short8*)&ks[r][c8 * 8] = pk[it];
    *(short8*)&vt[r][c8 * 8] = pv[it];
  }

  for (int kt = 0; kt <= kt_max; ++kt) {
    __syncthreads();                        // staged tile visible
    if (kt < kt_max) {                      // prefetch next tile to regs
#pragma unroll
      for (int it = 0; it < 4; ++it) {
        int idx = t + it * 128;
        int r = idx >> 3, c8 = idx & 7;
        pk[it] = *(const short8*)(kb + (long)((kt + 1) * 64 + r) * H + c8 * 8);
        pv[it] = *(const short8*)(vb + (long)r * S + (kt + 1) * 64 + c8 * 8);
      }
    }
    // ---- S = Q K^T ----
    f32x4 sc[4];
#pragma unroll
    for (int c = 0; c < 4; ++c) sc[c] = f32x4{0.f, 0.f, 0.f, 0.f};
#pragma unroll
    for (int c = 0; c < 4; ++c)
#pragma unroll
      for (int kh = 0; kh < 2; ++kh) {
        short8 bk = *(const short8*)&ks[c * 16 + l15][kh * 32 + g * 8];
        sc[c] = __builtin_amdgcn_mfma_f32_16x16x32_bf16(kh ? aq1 : aq0, bk, sc[c], 0, 0, 0);
      }
    if (kt == kt_max) {                     // only diagonal tile masks
#pragma unroll
      for (int c = 0; c < 4; ++c)
#pragma unroll
        for (int r = 0; r < 4; ++r)
          if (kt * 64 + c * 16 + l15 > qt * 32 + w * 16 + g * 4 + r) sc[c][r] = -1e30f;
    }
    // ---- online softmax (row=(lane>>4)*4+r; reduce over 16 lanes) ----
    float al[4];
#pragma unroll
    for (int r = 0; r < 4; ++r) {
      float mx = fmaxf(fmaxf(sc[0][r], sc[1][r]), fmaxf(sc[2][r], sc[3][r]));
#pragma unroll
      for (int off = 8; off > 0; off >>= 1) mx = fmaxf(mx, __shfl_xor(mx, off));
      float mn = fmaxf(m_[r], mx);
      al[r] = exp2f((m_[r] - mn) * LOG2E);
      float sum = 0.f;
#pragma unroll
      for (int c = 0; c < 4; ++c) {
        float p = exp2f((sc[c][r] - mn) * LOG2E);
        sc[c][r] = p;
        sum += p;
      }
#pragma unroll
      for (int off = 8; off > 0; off >>= 1) sum += __shfl_xor(sum, off);
      l_[r] = l_[r] * al[r] + sum;
      m_[r] = mn;
    }
    // ---- P -> LDS (same-wave rows), rescale O ----
#pragma unroll
    for (int c = 0; c < 4; ++c)
#pragma unroll
      for (int r = 0; r < 4; ++r)
        pl[w * 16 + g * 4 + r][c * 16 + l15] = f2bf(sc[c][r]);
#pragma unroll
    for (int c = 0; c < 4; ++c)
#pragma unroll
      for (int r = 0; r < 4; ++r) O[c][r] *= al[r];
    // ---- O += P V ----
#pragma unroll
    for (int kh = 0; kh < 2; ++kh) {
      short8 ap = *(const short8*)&pl[w * 16 + l15][kh * 32 + g * 8];
#pragma unroll
      for (int c = 0; c < 4; ++c) {
        short8 bv = *(const short8*)&vt[c * 16 + l15][kh * 32 + g * 8];
        O[c] = __builtin_amdgcn_mfma_f32_16x16x32_bf16(ap, bv, O[c], 0, 0, 0);
      }
    }
    __syncthreads();                        // reads done; safe to overwrite
    if (kt < kt_max) {
#pragma unroll
      for (int it = 0; it < 4; ++it) {
        int idx = t + it * 128;
        int r = idx >> 3, c8 = idx & 7;
        *(short8*)&ks[r][c8 * 8] = pk[it];
        *(short8*)&vt[r][c8 * 8] = pv[it];
      }
    }
  }
#pragma unroll
  for (int r = 0; r < 4; ++r) {
    float inv = 1.0f / l_[r];
    long row = (long)b * S + qt * 32 + w * 16 + g * 4 + r;
#pragma unroll
    for (int c = 0; c < 4; ++c)
      out[row * H + c * 16 + l15] = O[c][r] * inv;
  }
}

extern "C" void kernel_launch(void* const* d_in, const int* in_sizes, int n_in,
                              void* d_out, int out_size, void* d_ws, size_t ws_size,
                              hipStream_t stream) {
  const float* x  = (const float*)d_in[0];
  const float* Wq = (const float*)d_in[1];
  const float* Wk = (const float*)d_in[2];
  const float* Wv = (const float*)d_in[3];
  float* outp = (float*)d_out;
  unsigned short* WT3 = (unsigned short*)d_ws;                    // 384 KB
  unsigned short* q  = (unsigned short*)((char*)d_ws + 512 * 1024);  // 2 MB each
  unsigned short* kk = q + (size_t)Bn * S * H;
  unsigned short* vT = kk + (size_t)Bn * S * H;
  wtrans_kernel<<<dim3(48), dim3(256), 0, stream>>>(Wq, Wk, Wv, WT3);
  qkv_kernel<<<dim3((Bn * S) / 32), dim3(128), 0, stream>>>(x, WT3, q, kk, vT);
  attn_kernel<<<dim3(Bn * (S / 32) * 1), dim3(128), 0, stream>>>(q, kk, vT, outp);
}

// Round 4
// 233.131 us; speedup vs baseline: 1.0379x; 1.0379x over previous
//
#include <hip/hip_runtime.h>

constexpr int Bn = 8, S = 2048, E = 1024, H = 64;
constexpr float SCALE = 0.03125f;     // E^-0.5 (folded into q)
constexpr float LOG2E = 1.44269504f;

typedef __attribute__((ext_vector_type(8))) short short8;  // 8 bf16
typedef __attribute__((ext_vector_type(4))) float f32x4;   // MFMA C/D

__device__ __forceinline__ unsigned short f2bf(float f) {
  unsigned u = __builtin_bit_cast(unsigned, f);
  u += 0x7fffu + ((u >> 16) & 1u);    // RNE
  return (unsigned short)(u >> 16);
}
__device__ __forceinline__ ushort4 f4bf(float4 f) {
  return make_ushort4(f2bf(f.x), f2bf(f.y), f2bf(f.z), f2bf(f.w));
}
__device__ __forceinline__ short8 pack8(float4 a, float4 b) {
  short8 r;
  r[0] = (short)f2bf(a.x); r[1] = (short)f2bf(a.y);
  r[2] = (short)f2bf(a.z); r[3] = (short)f2bf(a.w);
  r[4] = (short)f2bf(b.x); r[5] = (short)f2bf(b.y);
  r[6] = (short)f2bf(b.z); r[7] = (short)f2bf(b.w);
  return r;
}

// ---------- W [1024][64] fp32 -> WT3 [3][64][1024] bf16 ----------
__global__ __launch_bounds__(256) void wtrans_kernel(
    const float* __restrict__ Wq, const float* __restrict__ Wk,
    const float* __restrict__ Wv, unsigned short* __restrict__ WT3) {
  __shared__ unsigned short tb[64][72];
  const int m = blockIdx.x >> 4;
  const int e0 = (blockIdx.x & 15) * 64;
  const float* W = (m == 0) ? Wq : (m == 1) ? Wk : Wv;
  const int t = threadIdx.x;
#pragma unroll
  for (int it = 0; it < 4; ++it) {
    int idx = t + it * 256;
    int r = idx >> 4, c4 = idx & 15;
    float4 f = ((const float4*)(W + (long)(e0 + r) * H))[c4];
    *(ushort4*)&tb[r][c4 * 4] = f4bf(f);
  }
  __syncthreads();
#pragma unroll
  for (int it = 0; it < 4; ++it) {
    int idx = t + it * 256;
    int h = idx >> 4, e4 = idx & 15;
    ushort4 u = make_ushort4(tb[e4 * 4 + 0][h], tb[e4 * 4 + 1][h],
                             tb[e4 * 4 + 2][h], tb[e4 * 4 + 3][h]);
    ((ushort4*)(WT3 + (long)(m * 64 + h) * E + e0))[e4] = u;
  }
}

// ---------- QKV: no LDS, no barriers, 24 waves/CU ----------
// Block = 384 thr (6 waves) sharing one 16-row x stripe (L1). Wave w owns
// col-tiles j=2w,2w+1 of the 192 concatenated q|k|v columns (8 acc VGPRs).
// B row for tile j is simply WT3 row 16j+l15. Outputs: q bf16 (pre-scaled),
// k bf16 [s][h], vT bf16 [b][h][s].
__global__ __launch_bounds__(384) void qkv_kernel(
    const float* __restrict__ x, const unsigned short* __restrict__ WT3,
    unsigned short* __restrict__ q, unsigned short* __restrict__ kk,
    unsigned short* __restrict__ vT) {
  const int t = threadIdx.x;
  const int w = t >> 6, lane = t & 63, l15 = lane & 15, g = lane >> 4;
  const long row0 = (long)blockIdx.x * 16;
  const float* xr = x + (row0 + l15) * E + g * 8;

  f32x4 acc[2];
  acc[0] = f32x4{0.f, 0.f, 0.f, 0.f};
  acc[1] = f32x4{0.f, 0.f, 0.f, 0.f};

  // depth-2 prefetch of the x stripe (4 float4 per chunk per lane)
  float4 xf[4], xg[4];
#pragma unroll
  for (int u = 0; u < 4; ++u) {
    xf[u] = *(const float4*)(xr + (u >> 1) * 32 + (u & 1) * 4);
    xg[u] = *(const float4*)(xr + 64 + (u >> 1) * 32 + (u & 1) * 4);
  }
  const unsigned short* wb0 = WT3 + (long)(16 * (2 * w + 0) + l15) * E + g * 8;
  const unsigned short* wb1 = WT3 + (long)(16 * (2 * w + 1) + l15) * E + g * 8;

  for (int c = 0; c < 16; ++c) {
    short8 a0 = pack8(xf[0], xf[1]);
    short8 a1 = pack8(xf[2], xf[3]);
#pragma unroll
    for (int u = 0; u < 4; ++u) xf[u] = xg[u];
    if (c + 2 < 16) {
      const float* p = xr + (c + 2) * 64;
#pragma unroll
      for (int u = 0; u < 4; ++u)
        xg[u] = *(const float4*)(p + (u >> 1) * 32 + (u & 1) * 4);
    }
    short8 b00 = *(const short8*)(wb0 + c * 64);
    short8 b01 = *(const short8*)(wb0 + c * 64 + 32);
    short8 b10 = *(const short8*)(wb1 + c * 64);
    short8 b11 = *(const short8*)(wb1 + c * 64 + 32);
    acc[0] = __builtin_amdgcn_mfma_f32_16x16x32_bf16(a0, b00, acc[0], 0, 0, 0);
    acc[0] = __builtin_amdgcn_mfma_f32_16x16x32_bf16(a1, b01, acc[0], 0, 0, 0);
    acc[1] = __builtin_amdgcn_mfma_f32_16x16x32_bf16(a0, b10, acc[1], 0, 0, 0);
    acc[1] = __builtin_amdgcn_mfma_f32_16x16x32_bf16(a1, b11, acc[1], 0, 0, 0);
  }

  const int bb = (int)(row0 >> 11);
  const int sl = (int)(row0 & 2047) + g * 4;
#pragma unroll
  for (int jt = 0; jt < 2; ++jt) {
    const int j = 2 * w + jt;
    const int mm = j >> 2;
    const int col = (j & 3) * 16 + l15;
    if (mm == 0) {
#pragma unroll
      for (int r = 0; r < 4; ++r)
        q[(row0 + g * 4 + r) * H + col] = f2bf(acc[jt][r] * SCALE);
    } else if (mm == 1) {
#pragma unroll
      for (int r = 0; r < 4; ++r)
        kk[(row0 + g * 4 + r) * H + col] = f2bf(acc[jt][r]);
    } else {
      ushort4 v4 = make_ushort4(f2bf(acc[jt][0]), f2bf(acc[jt][1]),
                                f2bf(acc[jt][2]), f2bf(acc[jt][3]));
      *(ushort4*)(vT + ((long)bb * H + col) * S + sl) = v4;
    }
  }
}

// ---------- barrier-free K-split flash attention ----------
// grid 1024: b = blockIdx&7 (== XCD -> K/V L2-local), qt = blockIdx>>3
// (0..127, 16 q-rows each). Block = 4 waves = 4 key-splits; wave w scans
// 32-key chunks ch = w, w+4, ... independently (own online softmax, no
// barriers); single LDS merge at the end.
__global__ __launch_bounds__(256) void attn_kernel(
    const unsigned short* __restrict__ q, const unsigned short* __restrict__ k,
    const unsigned short* __restrict__ vT, float* __restrict__ out) {
  __shared__ float Os[4][16][68];           // pad 68: g-groups 16 banks apart
  __shared__ float ms[4][16], ls[4][16];
  __shared__ unsigned short pl[4][16][40];  // per-wave P tile, pad 40
  const int t = threadIdx.x;
  const int w = t >> 6, lane = t & 63, l15 = lane & 15, g = lane >> 4;
  const int b = blockIdx.x & 7, qt = blockIdx.x >> 3;
  const int qrow0 = qt * 16;
  const unsigned short* qb = q + ((long)b * S + qrow0 + l15) * H + g * 8;
  const unsigned short* kb = k + (long)b * S * H;
  const unsigned short* vb = vT + (long)b * H * S;

  short8 aq0 = *(const short8*)qb;
  short8 aq1 = *(const short8*)(qb + 32);

  f32x4 O[4];
  float m_[4], l_[4];
#pragma unroll
  for (int c = 0; c < 4; ++c) O[c] = f32x4{0.f, 0.f, 0.f, 0.f};
#pragma unroll
  for (int r = 0; r < 4; ++r) { m_[r] = -1e30f; l_[r] = 0.f; }

  const int nch = (16 * qt + 47) >> 5;      // 32-key chunks to cover keys<=rows
  for (int ch = w; ch < nch; ch += 4) {
    const int k0 = ch * 32;
    // ---- S[16 x 32] = Q K^T ----
    f32x4 sc[2];
    sc[0] = f32x4{0.f, 0.f, 0.f, 0.f};
    sc[1] = f32x4{0.f, 0.f, 0.f, 0.f};
#pragma unroll
    for (int c = 0; c < 2; ++c) {
      const unsigned short* kp = kb + (long)(k0 + c * 16 + l15) * H + g * 8;
      short8 bk0 = *(const short8*)kp;
      short8 bk1 = *(const short8*)(kp + 32);
      sc[c] = __builtin_amdgcn_mfma_f32_16x16x32_bf16(aq0, bk0, sc[c], 0, 0, 0);
      sc[c] = __builtin_amdgcn_mfma_f32_16x16x32_bf16(aq1, bk1, sc[c], 0, 0, 0);
    }
    if (k0 + 31 > qrow0) {                  // chunk touches the diagonal
#pragma unroll
      for (int c = 0; c < 2; ++c)
#pragma unroll
        for (int r = 0; r < 4; ++r)
          if (k0 + c * 16 + l15 > qrow0 + g * 4 + r) sc[c][r] = -1e30f;
    }
    // ---- per-row online softmax (reduce over 16 lanes of l15) ----
    float alr[4];
#pragma unroll
    for (int r = 0; r < 4; ++r) {
      float mx = fmaxf(sc[0][r], sc[1][r]);
#pragma unroll
      for (int off = 8; off > 0; off >>= 1) mx = fmaxf(mx, __shfl_xor(mx, off));
      float mn = fmaxf(m_[r], mx);
      float valid = (mn > -1e29f) ? 1.0f : 0.0f;   // all-masked-chunk guard
      alr[r] = exp2f((m_[r] - mn) * LOG2E);
      float p0 = exp2f((sc[0][r] - mn) * LOG2E) * valid;
      float p1 = exp2f((sc[1][r] - mn) * LOG2E) * valid;
      float sum = p0 + p1;
#pragma unroll
      for (int off = 8; off > 0; off >>= 1) sum += __shfl_xor(sum, off);
      l_[r] = l_[r] * alr[r] + sum;
      m_[r] = mn;
      sc[0][r] = p0;
      sc[1][r] = p1;
    }
    // ---- P -> per-wave LDS, O rescale ----
#pragma unroll
    for (int c = 0; c < 2; ++c)
#pragma unroll
      for (int r = 0; r < 4; ++r)
        pl[w][g * 4 + r][c * 16 + l15] = f2bf(sc[c][r]);
#pragma unroll
    for (int c = 0; c < 4; ++c)
#pragma unroll
      for (int r = 0; r < 4; ++r) O[c][r] *= alr[r];
    // ---- O += P V  (A from pl, K=32; B from vT, key-contiguous) ----
    short8 ap = *(const short8*)&pl[w][l15][g * 8];
#pragma unroll
    for (int c = 0; c < 4; ++c) {
      short8 bv = *(const short8*)(vb + (long)(c * 16 + l15) * S + k0 + g * 8);
      O[c] = __builtin_amdgcn_mfma_f32_16x16x32_bf16(ap, bv, O[c], 0, 0, 0);
    }
  }

  // ---- write split-partials, single barrier, merge ----
  if (l15 == 0) {
#pragma unroll
    for (int r = 0; r < 4; ++r) { ms[w][g * 4 + r] = m_[r]; ls[w][g * 4 + r] = l_[r]; }
  }
#pragma unroll
  for (int c = 0; c < 4; ++c)
#pragma unroll
    for (int r = 0; r < 4; ++r)
      Os[w][g * 4 + r][c * 16 + l15] = O[c][r];
  __syncthreads();
#pragma unroll
  for (int rr = 0; rr < 4; ++rr) {
    const int row = w * 4 + rr;
    float m0 = ms[0][row], m1 = ms[1][row], m2 = ms[2][row], m3 = ms[3][row];
    float mstar = fmaxf(fmaxf(m0, m1), fmaxf(m2, m3));
    float f0 = exp2f((m0 - mstar) * LOG2E), f1 = exp2f((m1 - mstar) * LOG2E);
    float f2 = exp2f((m2 - mstar) * LOG2E), f3 = exp2f((m3 - mstar) * LOG2E);
    float lstar = ls[0][row] * f0 + ls[1][row] * f1 + ls[2][row] * f2 + ls[3][row] * f3;
    float o = Os[0][row][lane] * f0 + Os[1][row][lane] * f1 +
              Os[2][row][lane] * f2 + Os[3][row][lane] * f3;
    out[((long)b * S + qrow0 + row) * H + lane] = o / lstar;
  }
}

extern "C" void kernel_launch(void* const* d_in, const int* in_sizes, int n_in,
                              void* d_out, int out_size, void* d_ws, size_t ws_size,
                              hipStream_t stream) {
  const float* x  = (const float*)d_in[0];
  const float* Wq = (const float*)d_in[1];
  const float* Wk = (const float*)d_in[2];
  const float* Wv = (const float*)d_in[3];
  float* outp = (float*)d_out;
  unsigned short* WT3 = (unsigned short*)d_ws;                       // 384 KB
  unsigned short* q  = (unsigned short*)((char*)d_ws + 512 * 1024);  // 2 MB each
  unsigned short* kk = q + (size_t)Bn * S * H;
  unsigned short* vT = kk + (size_t)Bn * S * H;
  wtrans_kernel<<<dim3(48), dim3(256), 0, stream>>>(Wq, Wk, Wv, WT3);
  qkv_kernel<<<dim3((Bn * S) / 16), dim3(384), 0, stream>>>(x, WT3, q, kk, vT);
  attn_kernel<<<dim3(Bn * (S / 16)), dim3(256), 0, stream>>>(q, kk, vT, outp);
}

// Round 5
// 182.517 us; speedup vs baseline: 1.3257x; 1.2773x over previous
//
#include <hip/hip_runtime.h>

constexpr int Bn = 8, S = 2048, E = 1024, H = 64;
constexpr float SCALE = 0.03125f;     // E^-0.5 (folded into q)
constexpr float LOG2E = 1.44269504f;

typedef __attribute__((ext_vector_type(8))) short short8;  // 8 bf16
typedef __attribute__((ext_vector_type(4))) float f32x4;   // MFMA C/D

__device__ __forceinline__ unsigned short f2bf(float f) {
  unsigned u = __builtin_bit_cast(unsigned, f);
  u += 0x7fffu + ((u >> 16) & 1u);    // RNE
  return (unsigned short)(u >> 16);
}
__device__ __forceinline__ ushort4 f4bf(float4 f) {
  return make_ushort4(f2bf(f.x), f2bf(f.y), f2bf(f.z), f2bf(f.w));
}

// ---------- W [1024][64] fp32 -> WT3 [3][64][1024] bf16 ----------
__global__ __launch_bounds__(256) void wtrans_kernel(
    const float* __restrict__ Wq, const float* __restrict__ Wk,
    const float* __restrict__ Wv, unsigned short* __restrict__ WT3) {
  __shared__ unsigned short tb[64][72];
  const int m = blockIdx.x >> 4;
  const int e0 = (blockIdx.x & 15) * 64;
  const float* W = (m == 0) ? Wq : (m == 1) ? Wk : Wv;
  const int t = threadIdx.x;
#pragma unroll
  for (int it = 0; it < 4; ++it) {
    int idx = t + it * 256;
    int r = idx >> 4, c4 = idx & 15;
    float4 f = ((const float4*)(W + (long)(e0 + r) * H))[c4];
    *(ushort4*)&tb[r][c4 * 4] = f4bf(f);
  }
  __syncthreads();
#pragma unroll
  for (int it = 0; it < 4; ++it) {
    int idx = t + it * 256;
    int h = idx >> 4, e4 = idx & 15;
    ushort4 u = make_ushort4(tb[e4 * 4 + 0][h], tb[e4 * 4 + 1][h],
                             tb[e4 * 4 + 2][h], tb[e4 * 4 + 3][h]);
    ((ushort4*)(WT3 + (long)(m * 64 + h) * E + e0))[e4] = u;
  }
}

// ---------- QKV: LDS-staged, fully coalesced, m97 2-barrier loop ----------
// grid 512 x 256thr (2 blocks/CU). Tile = 32 seq-rows x 192 cols.
// Wave w owns all 32 rows x cols [w*48, w*48+48) (3 col-tiles); waves share
// the A (x) tile. All global loads are lane-contiguous (dense granules).
__global__ __launch_bounds__(256) void qkv_kernel(
    const float* __restrict__ x, const unsigned short* __restrict__ WT3,
    unsigned short* __restrict__ q, unsigned short* __restrict__ kk,
    unsigned short* __restrict__ vT) {
  __shared__ unsigned short xs[32][72];    // [seq-row][e]  (pad 72)
  __shared__ unsigned short ws[192][72];   // [out-col j][e]
  const int t = threadIdx.x;
  const int w = t >> 6, lane = t & 63, l15 = lane & 15, g = lane >> 4;
  const long row0 = (long)blockIdx.x * 32;

  f32x4 acc[2][3];
#pragma unroll
  for (int rt = 0; rt < 2; ++rt)
#pragma unroll
    for (int ct = 0; ct < 3; ++ct) acc[rt][ct] = f32x4{0.f, 0.f, 0.f, 0.f};

  float4 px[2];        // x chunk: 32x64 fp32 = 8 KB = 2 float4/thread
  short8 pw[6];        // W chunk: 192x64 bf16 = 24 KB = 6 short8/thread
  const int xrow = t >> 4, xc4 = t & 15;         // +16 rows on it=1
  const int wrow = t >> 3, wc8 = t & 7;          // +32 rows per it

  // prologue: chunk 0 -> regs -> LDS
#pragma unroll
  for (int it = 0; it < 2; ++it)
    px[it] = ((const float4*)(x + (row0 + xrow + it * 16) * E))[xc4];
#pragma unroll
  for (int it = 0; it < 6; ++it)
    pw[it] = *(const short8*)(WT3 + (long)(wrow + it * 32) * E + wc8 * 8);
#pragma unroll
  for (int it = 0; it < 2; ++it)
    *(ushort4*)&xs[xrow + it * 16][xc4 * 4] = f4bf(px[it]);
#pragma unroll
  for (int it = 0; it < 6; ++it)
    *(short8*)&ws[wrow + it * 32][wc8 * 8] = pw[it];

  for (int c = 0; c < 16; ++c) {
    __syncthreads();                       // staged chunk visible
    if (c < 15) {                          // prefetch next chunk (coalesced)
      const int e0 = (c + 1) * 64;
#pragma unroll
      for (int it = 0; it < 2; ++it)
        px[it] = ((const float4*)(x + (row0 + xrow + it * 16) * E + e0))[xc4];
#pragma unroll
      for (int it = 0; it < 6; ++it)
        pw[it] = *(const short8*)(WT3 + (long)(wrow + it * 32) * E + e0 + wc8 * 8);
    }
#pragma unroll
    for (int kh = 0; kh < 2; ++kh) {
      short8 a0 = *(const short8*)&xs[l15][kh * 32 + g * 8];
      short8 a1 = *(const short8*)&xs[16 + l15][kh * 32 + g * 8];
#pragma unroll
      for (int ct = 0; ct < 3; ++ct) {
        short8 b = *(const short8*)&ws[w * 48 + ct * 16 + l15][kh * 32 + g * 8];
        acc[0][ct] = __builtin_amdgcn_mfma_f32_16x16x32_bf16(a0, b, acc[0][ct], 0, 0, 0);
        acc[1][ct] = __builtin_amdgcn_mfma_f32_16x16x32_bf16(a1, b, acc[1][ct], 0, 0, 0);
      }
    }
    __syncthreads();                       // LDS reads done
    if (c < 15) {
#pragma unroll
      for (int it = 0; it < 2; ++it)
        *(ushort4*)&xs[xrow + it * 16][xc4 * 4] = f4bf(px[it]);
#pragma unroll
      for (int it = 0; it < 6; ++it)
        *(short8*)&ws[wrow + it * 32][wc8 * 8] = pw[it];
    }
  }

  const int bb = (int)(row0 >> 11);
  const int srow = (int)(row0 & 2047);
#pragma unroll
  for (int ct = 0; ct < 3; ++ct) {
    const int col = w * 48 + ct * 16 + l15;
    const int mm = col >> 6, ch = col & 63;
#pragma unroll
    for (int rt = 0; rt < 2; ++rt) {
      const int srl = rt * 16 + g * 4;
      if (mm == 0) {
#pragma unroll
        for (int r = 0; r < 4; ++r)
          q[(row0 + srl + r) * H + ch] = f2bf(acc[rt][ct][r] * SCALE);
      } else if (mm == 1) {
#pragma unroll
        for (int r = 0; r < 4; ++r)
          kk[(row0 + srl + r) * H + ch] = f2bf(acc[rt][ct][r]);
      } else {
        ushort4 v4 = make_ushort4(f2bf(acc[rt][ct][0]), f2bf(acc[rt][ct][1]),
                                  f2bf(acc[rt][ct][2]), f2bf(acc[rt][ct][3]));
        *(ushort4*)(vT + ((long)bb * H + ch) * S + srow + srl) = v4;
      }
    }
  }
}

// ---------- causal flash attention: Q64 tiles, uniform 2-pass schedule ----
// grid 256: b = blockIdx&7, p = blockIdx>>3 (0..31). Block runs qt=p then
// qt=31-p: exactly 33 K64-tile iterations for every block. 4 waves; wave w
// owns q-rows w*16..w*16+15. All staging dense short8 (vT is precomputed).
__global__ __launch_bounds__(256) void attn_kernel(
    const unsigned short* __restrict__ q, const unsigned short* __restrict__ k,
    const unsigned short* __restrict__ vT, float* __restrict__ out) {
  __shared__ unsigned short ks[64][72];   // [key][h]
  __shared__ unsigned short vt[64][72];   // [h][key]
  __shared__ unsigned short pl[64][72];   // [qrow][key], per-wave rows
  const int t = threadIdx.x;
  const int w = t >> 6, lane = t & 63, l15 = lane & 15, g = lane >> 4;
  const int b = blockIdx.x & 7, p = blockIdx.x >> 3;
  const unsigned short* kb = k + (long)b * S * H;
  const unsigned short* vb = vT + (long)b * H * S;
  const int srow = t >> 3, sc8 = t & 7;   // staging: 64x64 bf16 = 2 short8/thr

  int qtv = p;
  const unsigned short* qb = q + ((long)b * S + qtv * 64 + w * 16 + l15) * H + g * 8;
  short8 aq0 = *(const short8*)qb;
  short8 aq1 = *(const short8*)(qb + 32);

  f32x4 O[4];
  float m_[4], l_[4];
#pragma unroll
  for (int c = 0; c < 4; ++c) O[c] = f32x4{0.f, 0.f, 0.f, 0.f};
#pragma unroll
  for (int r = 0; r < 4; ++r) { m_[r] = -1e30f; l_[r] = 0.f; }

  short8 pk[2], pv[2];
  // prologue: tile (pass0, kt=0)
#pragma unroll
  for (int it = 0; it < 2; ++it) {
    pk[it] = *(const short8*)(kb + (long)(srow + it * 32) * H + sc8 * 8);
    pv[it] = *(const short8*)(vb + (long)(srow + it * 32) * S + sc8 * 8);
  }
#pragma unroll
  for (int it = 0; it < 2; ++it) {
    *(short8*)&ks[srow + it * 32][sc8 * 8] = pk[it];
    *(short8*)&vt[srow + it * 32][sc8 * 8] = pv[it];
  }

  for (int ti = 0; ti < 33; ++ti) {
    const int pass = (ti <= p) ? 0 : 1;
    const int kt = pass ? (ti - p - 1) : ti;
    qtv = pass ? (31 - p) : p;
    const int qrow0 = qtv * 64;
    const bool diag = (ti == p) || (ti == 32);
    __syncthreads();                        // staged tile visible
    if (ti < 32) {                          // prefetch next linearized tile
      const int np = (ti + 1 <= p) ? 0 : 1;
      const int nk = np ? (ti - p) : (ti + 1);
      const long ko = (long)nk * 64;
#pragma unroll
      for (int it = 0; it < 2; ++it) {
        pk[it] = *(const short8*)(kb + (ko + srow + it * 32) * H + sc8 * 8);
        pv[it] = *(const short8*)(vb + (long)(srow + it * 32) * S + ko + sc8 * 8);
      }
    }
    // ---- S = Q K^T ----
    f32x4 sc[4];
#pragma unroll
    for (int c = 0; c < 4; ++c) sc[c] = f32x4{0.f, 0.f, 0.f, 0.f};
#pragma unroll
    for (int c = 0; c < 4; ++c)
#pragma unroll
      for (int kh = 0; kh < 2; ++kh) {
        short8 bk = *(const short8*)&ks[c * 16 + l15][kh * 32 + g * 8];
        sc[c] = __builtin_amdgcn_mfma_f32_16x16x32_bf16(kh ? aq1 : aq0, bk, sc[c], 0, 0, 0);
      }
    if (diag) {
#pragma unroll
      for (int c = 0; c < 4; ++c)
#pragma unroll
        for (int r = 0; r < 4; ++r)
          if (kt * 64 + c * 16 + l15 > qrow0 + w * 16 + g * 4 + r) sc[c][r] = -1e30f;
    }
    // ---- online softmax (reduce over the 16 l15 lanes) ----
    float al[4];
#pragma unroll
    for (int r = 0; r < 4; ++r) {
      float mx = fmaxf(fmaxf(sc[0][r], sc[1][r]), fmaxf(sc[2][r], sc[3][r]));
#pragma unroll
      for (int off = 8; off > 0; off >>= 1) mx = fmaxf(mx, __shfl_xor(mx, off));
      float mn = fmaxf(m_[r], mx);
      al[r] = exp2f((m_[r] - mn) * LOG2E);
      float sum = 0.f;
#pragma unroll
      for (int c = 0; c < 4; ++c) {
        float pe = exp2f((sc[c][r] - mn) * LOG2E);
        sc[c][r] = pe;
        sum += pe;
      }
#pragma unroll
      for (int off = 8; off > 0; off >>= 1) sum += __shfl_xor(sum, off);
      l_[r] = l_[r] * al[r] + sum;
      m_[r] = mn;
    }
    // ---- P -> per-wave LDS rows (wave-coherent), rescale O ----
#pragma unroll
    for (int c = 0; c < 4; ++c)
#pragma unroll
      for (int r = 0; r < 4; ++r)
        pl[w * 16 + g * 4 + r][c * 16 + l15] = f2bf(sc[c][r]);
#pragma unroll
    for (int c = 0; c < 4; ++c)
#pragma unroll
      for (int r = 0; r < 4; ++r) O[c][r] *= al[r];
    // ---- O += P V ----
#pragma unroll
    for (int kh = 0; kh < 2; ++kh) {
      short8 ap = *(const short8*)&pl[w * 16 + l15][kh * 32 + g * 8];
#pragma unroll
      for (int c = 0; c < 4; ++c) {
        short8 bv = *(const short8*)&vt[c * 16 + l15][kh * 32 + g * 8];
        O[c] = __builtin_amdgcn_mfma_f32_16x16x32_bf16(ap, bv, O[c], 0, 0, 0);
      }
    }
    if (diag) {                             // end of a pass: emit + reset
#pragma unroll
      for (int r = 0; r < 4; ++r) {
        float inv = 1.0f / l_[r];
        long row = (long)b * S + qrow0 + w * 16 + g * 4 + r;
#pragma unroll
        for (int c = 0; c < 4; ++c)
          out[row * H + c * 16 + l15] = O[c][r] * inv;
      }
#pragma unroll
      for (int c = 0; c < 4; ++c) O[c] = f32x4{0.f, 0.f, 0.f, 0.f};
#pragma unroll
      for (int r = 0; r < 4; ++r) { m_[r] = -1e30f; l_[r] = 0.f; }
      if (ti == p) {                        // load Q frags for pass 1
        const unsigned short* qb2 =
            q + ((long)b * S + (31 - p) * 64 + w * 16 + l15) * H + g * 8;
        aq0 = *(const short8*)qb2;
        aq1 = *(const short8*)(qb2 + 32);
      }
    }
    __syncthreads();                        // LDS reads done
    if (ti < 32) {
#pragma unroll
      for (int it = 0; it < 2; ++it) {
        *(short8*)&ks[srow + it * 32][sc8 * 8] = pk[it];
        *(short8*)&vt[srow + it * 32][sc8 * 8] = pv[it];
      }
    }
  }
}

extern "C" void kernel_launch(void* const* d_in, const int* in_sizes, int n_in,
                              void* d_out, int out_size, void* d_ws, size_t ws_size,
                              hipStream_t stream) {
  const float* x  = (const float*)d_in[0];
  const float* Wq = (const float*)d_in[1];
  const float* Wk = (const float*)d_in[2];
  const float* Wv = (const float*)d_in[3];
  float* outp = (float*)d_out;
  unsigned short* WT3 = (unsigned short*)d_ws;                       // 384 KB
  unsigned short* q  = (unsigned short*)((char*)d_ws + 512 * 1024);  // 2 MB each
  unsigned short* kk = q + (size_t)Bn * S * H;
  unsigned short* vT = kk + (size_t)Bn * S * H;
  wtrans_kernel<<<dim3(48), dim3(256), 0, stream>>>(Wq, Wk, Wv, WT3);
  qkv_kernel<<<dim3((Bn * S) / 32), dim3(256), 0, stream>>>(x, WT3, q, kk, vT);
  attn_kernel<<<dim3(Bn * (S / 64)), dim3(256), 0, stream>>>(q, kk, vT, outp);
}

// Round 6
// 172.878 us; speedup vs baseline: 1.3996x; 1.0558x over previous
//
#include <hip/hip_runtime.h>

constexpr int Bn = 8, S = 2048, E = 1024, H = 64;
constexpr float SCALE = 0.03125f;     // E^-0.5 (folded into q)
constexpr float LOG2E = 1.44269504f;

typedef __attribute__((ext_vector_type(8))) short short8;  // 8 bf16
typedef __attribute__((ext_vector_type(4))) float f32x4;   // MFMA C/D

__device__ __forceinline__ unsigned short f2bf(float f) {
  unsigned u = __builtin_bit_cast(unsigned, f);
  u += 0x7fffu + ((u >> 16) & 1u);    // RNE
  return (unsigned short)(u >> 16);
}
__device__ __forceinline__ ushort4 f4bf(float4 f) {
  return make_ushort4(f2bf(f.x), f2bf(f.y), f2bf(f.z), f2bf(f.w));
}

// ---------- W [1024][64] fp32 -> WT3 [3][64][1024] bf16 ----------
__global__ __launch_bounds__(256) void wtrans_kernel(
    const float* __restrict__ Wq, const float* __restrict__ Wk,
    const float* __restrict__ Wv, unsigned short* __restrict__ WT3) {
  __shared__ unsigned short tb[64][72];
  const int m = blockIdx.x >> 4;
  const int e0 = (blockIdx.x & 15) * 64;
  const float* W = (m == 0) ? Wq : (m == 1) ? Wk : Wv;
  const int t = threadIdx.x;
#pragma unroll
  for (int it = 0; it < 4; ++it) {
    int idx = t + it * 256;
    int r = idx >> 4, c4 = idx & 15;
    float4 f = ((const float4*)(W + (long)(e0 + r) * H))[c4];
    *(ushort4*)&tb[r][c4 * 4] = f4bf(f);
  }
  __syncthreads();
#pragma unroll
  for (int it = 0; it < 4; ++it) {
    int idx = t + it * 256;
    int h = idx >> 4, e4 = idx & 15;
    ushort4 u = make_ushort4(tb[e4 * 4 + 0][h], tb[e4 * 4 + 1][h],
                             tb[e4 * 4 + 2][h], tb[e4 * 4 + 3][h]);
    ((ushort4*)(WT3 + (long)(m * 64 + h) * E + e0))[e4] = u;
  }
}

// ---------- QKV: 16-row tiles, grid 1024 (16 waves/CU) ----------
// x chunk staged dense in tiny LDS; W B-frags direct from global (L1-hot).
// Wave w owns cols [w*48, w*48+48). Outputs: q bf16 (pre-scaled) [s][h],
// k bf16 [s][h], vT bf16 [b][h][s].
__global__ __launch_bounds__(256, 4) void qkv_kernel(
    const float* __restrict__ x, const unsigned short* __restrict__ WT3,
    unsigned short* __restrict__ q, unsigned short* __restrict__ kk,
    unsigned short* __restrict__ vT) {
  __shared__ unsigned short xs[16][72];
  const int t = threadIdx.x;
  const int w = t >> 6, lane = t & 63, l15 = lane & 15, g = lane >> 4;
  const long row0 = (long)blockIdx.x * 16;
  const int xr = t >> 4, xc = t & 15;    // 16 rows x 16 float4 = 4KB dense

  f32x4 acc[3];
#pragma unroll
  for (int ct = 0; ct < 3; ++ct) acc[ct] = f32x4{0.f, 0.f, 0.f, 0.f};

  float4 px = ((const float4*)(x + (row0 + xr) * E))[xc];
  *(ushort4*)&xs[xr][xc * 4] = f4bf(px);
  const unsigned short* wbase = WT3 + (long)(w * 48 + l15) * E + g * 8;

  for (int c = 0; c < 16; ++c) {
    __syncthreads();                     // staged chunk visible
    if (c < 15)                          // prefetch next chunk (dense)
      px = ((const float4*)(x + (row0 + xr) * E + (c + 1) * 64))[xc];
    short8 a0 = *(const short8*)&xs[l15][g * 8];
    short8 a1 = *(const short8*)&xs[l15][32 + g * 8];
#pragma unroll
    for (int ct = 0; ct < 3; ++ct) {
      short8 b0 = *(const short8*)(wbase + (long)(ct * 16) * E + c * 64);
      short8 b1 = *(const short8*)(wbase + (long)(ct * 16) * E + c * 64 + 32);
      acc[ct] = __builtin_amdgcn_mfma_f32_16x16x32_bf16(a0, b0, acc[ct], 0, 0, 0);
      acc[ct] = __builtin_amdgcn_mfma_f32_16x16x32_bf16(a1, b1, acc[ct], 0, 0, 0);
    }
    __syncthreads();                     // LDS reads done
    if (c < 15) *(ushort4*)&xs[xr][xc * 4] = f4bf(px);
  }

  const int bb = (int)(row0 >> 11);
  const int srow = (int)(row0 & 2047);
#pragma unroll
  for (int ct = 0; ct < 3; ++ct) {
    const int col = w * 48 + ct * 16 + l15;
    const int mm = col >> 6, ch = col & 63;
    if (mm == 0) {
#pragma unroll
      for (int r = 0; r < 4; ++r)
        q[(row0 + g * 4 + r) * H + ch] = f2bf(acc[ct][r] * SCALE);
    } else if (mm == 1) {
#pragma unroll
      for (int r = 0; r < 4; ++r)
        kk[(row0 + g * 4 + r) * H + ch] = f2bf(acc[ct][r]);
    } else {
      ushort4 v4 = make_ushort4(f2bf(acc[ct][0]), f2bf(acc[ct][1]),
                                f2bf(acc[ct][2]), f2bf(acc[ct][3]));
      *(ushort4*)(vT + ((long)bb * H + ch) * S + srow + g * 4) = v4;
    }
  }
}

// ---------- causal flash attention, S^T formulation, barrier-free loop ----
// S^T = K Q^T  =>  C col = l15 = q-row: per-lane scalar m/l/alpha, 2 shuffles
// per iteration. O^T = V^T P^T with V^T frags direct from vT. Wave =
// (qt 16-row tile, K-parity split); block = {qt=p, qt=127-p} x {split0,1};
// grid = 8 b x 64 p = 512. Single LDS merge of the two splits at the end.
__global__ __launch_bounds__(256, 2) void attn_kernel(
    const unsigned short* __restrict__ q, const unsigned short* __restrict__ k,
    const unsigned short* __restrict__ vT, float* __restrict__ out) {
  __shared__ unsigned short pl[4][16][72];  // per-wave P [qrow][key]
  __shared__ float Om[2][64][20];           // split-1 O^T [h][qrow]
  __shared__ float ms[2][16], ls[2][16];
  const int t = threadIdx.x;
  const int w = t >> 6, lane = t & 63, l15 = lane & 15, g = lane >> 4;
  const int b = blockIdx.x & 7, p = blockIdx.x >> 3;
  const int grp = w >> 1, sp = w & 1;       // qt-group, K-parity split
  const int qt = grp ? (127 - p) : p;       // p=0 (longest) dispatches first
  const int qrow0 = qt * 16;
  const int nt = (16 * qt + 79) >> 6;       // K64 tiles covering keys<=rows
  const unsigned short* kb = k + (long)b * S * H;
  const unsigned short* vb = vT + (long)b * H * S;
  const unsigned short* qp = q + ((long)b * S + qrow0 + l15) * H + g * 8;
  short8 bq0 = *(const short8*)qp;          // Q B-frags: n=l15=qrow, k=h
  short8 bq1 = *(const short8*)(qp + 32);

  f32x4 O[4];
#pragma unroll
  for (int c = 0; c < 4; ++c) O[c] = f32x4{0.f, 0.f, 0.f, 0.f};
  float m_ = -1e30f, l_ = 0.f;

  short8 ak[4][2];
  int kt = sp;
  if (kt < nt) {
#pragma unroll
    for (int c = 0; c < 4; ++c)
#pragma unroll
      for (int kh = 0; kh < 2; ++kh)
        ak[c][kh] = *(const short8*)(kb + (long)(kt * 64 + c * 16 + l15) * H + kh * 32 + g * 8);
  }

  for (; kt < nt; kt += 2) {
    // V^T A-frags issued early (consumed at the end of the iteration)
    short8 av[4][2];
#pragma unroll
    for (int c = 0; c < 4; ++c)
#pragma unroll
      for (int kh = 0; kh < 2; ++kh)
        av[c][kh] = *(const short8*)(vb + (long)(c * 16 + l15) * S + kt * 64 + kh * 32 + g * 8);
    // ---- S^T = K Q^T : D[m=key][n=qrow] ----
    f32x4 sc[4];
#pragma unroll
    for (int c = 0; c < 4; ++c) {
      sc[c] = f32x4{0.f, 0.f, 0.f, 0.f};
      sc[c] = __builtin_amdgcn_mfma_f32_16x16x32_bf16(ak[c][0], bq0, sc[c], 0, 0, 0);
      sc[c] = __builtin_amdgcn_mfma_f32_16x16x32_bf16(ak[c][1], bq1, sc[c], 0, 0, 0);
    }
    // prefetch K frags for kt+2
    if (kt + 2 < nt) {
#pragma unroll
      for (int c = 0; c < 4; ++c)
#pragma unroll
        for (int kh = 0; kh < 2; ++kh)
          ak[c][kh] = *(const short8*)(kb + (long)((kt + 2) * 64 + c * 16 + l15) * H + kh * 32 + g * 8);
    }
    if (kt == nt - 1) {                     // diagonal tile: mask key > qrow
#pragma unroll
      for (int c = 0; c < 4; ++c)
#pragma unroll
        for (int r = 0; r < 4; ++r)
          if (kt * 64 + c * 16 + g * 4 + r > qrow0 + l15) sc[c][r] = -1e30f;
    }
    // ---- per-lane softmax: 15 local ops + 2 shuffles each for max/sum ----
    float mx = -1e30f;
#pragma unroll
    for (int c = 0; c < 4; ++c)
#pragma unroll
      for (int r = 0; r < 4; ++r) mx = fmaxf(mx, sc[c][r]);
    mx = fmaxf(mx, __shfl_xor(mx, 16));
    mx = fmaxf(mx, __shfl_xor(mx, 32));
    float mn = fmaxf(m_, mx);
    float al = exp2f((m_ - mn) * LOG2E);
    float sum = 0.f;
#pragma unroll
    for (int c = 0; c < 4; ++c)
#pragma unroll
      for (int r = 0; r < 4; ++r) {
        float pe = exp2f((sc[c][r] - mn) * LOG2E);
        sc[c][r] = pe;
        sum += pe;
      }
    sum += __shfl_xor(sum, 16);
    sum += __shfl_xor(sum, 32);
    l_ = l_ * al + sum;
    m_ = mn;
    // ---- P^T -> per-wave LDS (4 ushort4 writes), O^T *= al (scalar) ----
#pragma unroll
    for (int c = 0; c < 4; ++c) {
      ushort4 p4 = make_ushort4(f2bf(sc[c][0]), f2bf(sc[c][1]),
                                f2bf(sc[c][2]), f2bf(sc[c][3]));
      *(ushort4*)&pl[w][l15][c * 16 + g * 4] = p4;
    }
#pragma unroll
    for (int c = 0; c < 4; ++c)
#pragma unroll
      for (int r = 0; r < 4; ++r) O[c][r] *= al;
    // ---- O^T += V^T P^T ----
    short8 bp0 = *(const short8*)&pl[w][l15][g * 8];
    short8 bp1 = *(const short8*)&pl[w][l15][32 + g * 8];
#pragma unroll
    for (int c = 0; c < 4; ++c) {
      O[c] = __builtin_amdgcn_mfma_f32_16x16x32_bf16(av[c][0], bp0, O[c], 0, 0, 0);
      O[c] = __builtin_amdgcn_mfma_f32_16x16x32_bf16(av[c][1], bp1, O[c], 0, 0, 0);
    }
  }

  // ---- merge the two K-parity splits of each qt ----
  if (sp == 1) {
#pragma unroll
    for (int c = 0; c < 4; ++c)
#pragma unroll
      for (int r = 0; r < 4; ++r)
        Om[grp][c * 16 + g * 4 + r][l15] = O[c][r];
    if (g == 0) { ms[grp][l15] = m_; ls[grp][l15] = l_; }
  }
  __syncthreads();
  if (sp == 0) {
    float m1 = ms[grp][l15], l1 = ls[grp][l15];
    float mstar = fmaxf(m_, m1);
    float f0 = exp2f((m_ - mstar) * LOG2E);
    float f1 = exp2f((m1 - mstar) * LOG2E);
    float inv = 1.0f / (l_ * f0 + l1 * f1);
    float* op = out + ((long)b * S + qrow0 + l15) * H;
#pragma unroll
    for (int c = 0; c < 4; ++c) {
      float4 o;
      o.x = (O[c][0] * f0 + Om[grp][c * 16 + g * 4 + 0][l15] * f1) * inv;
      o.y = (O[c][1] * f0 + Om[grp][c * 16 + g * 4 + 1][l15] * f1) * inv;
      o.z = (O[c][2] * f0 + Om[grp][c * 16 + g * 4 + 2][l15] * f1) * inv;
      o.w = (O[c][3] * f0 + Om[grp][c * 16 + g * 4 + 3][l15] * f1) * inv;
      *(float4*)(op + c * 16 + g * 4) = o;
    }
  }
}

extern "C" void kernel_launch(void* const* d_in, const int* in_sizes, int n_in,
                              void* d_out, int out_size, void* d_ws, size_t ws_size,
                              hipStream_t stream) {
  const float* x  = (const float*)d_in[0];
  const float* Wq = (const float*)d_in[1];
  const float* Wk = (const float*)d_in[2];
  const float* Wv = (const float*)d_in[3];
  float* outp = (float*)d_out;
  unsigned short* WT3 = (unsigned short*)d_ws;                       // 384 KB
  unsigned short* q  = (unsigned short*)((char*)d_ws + 512 * 1024);  // 2 MB each
  unsigned short* kk = q + (size_t)Bn * S * H;
  unsigned short* vT = kk + (size_t)Bn * S * H;
  wtrans_kernel<<<dim3(48), dim3(256), 0, stream>>>(Wq, Wk, Wv, WT3);
  qkv_kernel<<<dim3((Bn * S) / 16), dim3(256), 0, stream>>>(x, WT3, q, kk, vT);
  attn_kernel<<<dim3(Bn * 64), dim3(256), 0, stream>>>(q, kk, vT, outp);
}

// Round 7
// 141.121 us; speedup vs baseline: 1.7145x; 1.2250x over previous
//
#include <hip/hip_runtime.h>

constexpr int Bn = 8, S = 2048, E = 1024, H = 64;
constexpr float SCALE = 0.03125f;     // E^-0.5 (folded into q)
constexpr float LOG2E = 1.44269504f;

typedef __attribute__((ext_vector_type(8))) short short8;  // 8 bf16
typedef __attribute__((ext_vector_type(4))) float f32x4;   // MFMA C/D

__device__ __forceinline__ unsigned short f2bf(float f) {
  unsigned u = __builtin_bit_cast(unsigned, f);
  u += 0x7fffu + ((u >> 16) & 1u);    // RNE
  return (unsigned short)(u >> 16);
}
__device__ __forceinline__ ushort4 f4bf(float4 f) {
  return make_ushort4(f2bf(f.x), f2bf(f.y), f2bf(f.z), f2bf(f.w));
}

// ---------- W [1024][64] fp32 -> WT3 [3][64][1024] bf16 ----------
__global__ __launch_bounds__(256) void wtrans_kernel(
    const float* __restrict__ Wq, const float* __restrict__ Wk,
    const float* __restrict__ Wv, unsigned short* __restrict__ WT3) {
  __shared__ unsigned short tb[64][72];
  const int m = blockIdx.x >> 4;
  const int e0 = (blockIdx.x & 15) * 64;
  const float* W = (m == 0) ? Wq : (m == 1) ? Wk : Wv;
  const int t = threadIdx.x;
#pragma unroll
  for (int it = 0; it < 4; ++it) {
    int idx = t + it * 256;
    int r = idx >> 4, c4 = idx & 15;
    float4 f = ((const float4*)(W + (long)(e0 + r) * H))[c4];
    *(ushort4*)&tb[r][c4 * 4] = f4bf(f);
  }
  __syncthreads();
#pragma unroll
  for (int it = 0; it < 4; ++it) {
    int idx = t + it * 256;
    int h = idx >> 4, e4 = idx & 15;
    ushort4 u = make_ushort4(tb[e4 * 4 + 0][h], tb[e4 * 4 + 1][h],
                             tb[e4 * 4 + 2][h], tb[e4 * 4 + 3][h]);
    ((ushort4*)(WT3 + (long)(m * 64 + h) * E + e0))[e4] = u;
  }
}

// ---------- QKV GEMM, m97-style: M=32 x N=192, BK=128, LDS-dense ----------
// grid 512 (2 blocks/CU), 256 thr (4 waves). Both operands staged densely:
// x rows are 512B-contiguous runs, W rows 256B-contiguous runs. LDS row
// stride 136 shorts (+16B pad -> bank shift 4/row -> 2-way, free). Per wave
// per chunk: 24 MFMA, 20 ds_read_b128. Register prefetch across barriers.
__global__ __launch_bounds__(256) void qkv_kernel(
    const float* __restrict__ x, const unsigned short* __restrict__ WT3,
    unsigned short* __restrict__ q, unsigned short* __restrict__ kk,
    unsigned short* __restrict__ vT) {
  __shared__ unsigned short xs[32][136];    // [seq-row][e in chunk]
  __shared__ unsigned short ws[192][136];   // [out-col j][e in chunk]
  const int t = threadIdx.x;
  const int w = t >> 6, lane = t & 63, l15 = lane & 15, g = lane >> 4;
  const long row0 = (long)blockIdx.x * 32;
  const int xrow = t >> 5, xslot = t & 31;  // x: 8 rows x 32 float4 / iter
  const int wrow = t >> 4, wslot = t & 15;  // W: 16 rows x 16 short8 / iter

  f32x4 acc[2][3];
#pragma unroll
  for (int rt = 0; rt < 2; ++rt)
#pragma unroll
    for (int ct = 0; ct < 3; ++ct) acc[rt][ct] = f32x4{0.f, 0.f, 0.f, 0.f};

  float4 px[4];
  short8 pw[12];
  // prologue: chunk 0 -> regs -> LDS
#pragma unroll
  for (int it = 0; it < 4; ++it)
    px[it] = ((const float4*)(x + (row0 + xrow + it * 8) * E))[xslot];
#pragma unroll
  for (int it = 0; it < 12; ++it)
    pw[it] = *(const short8*)(WT3 + (long)(wrow + it * 16) * E + wslot * 8);
#pragma unroll
  for (int it = 0; it < 4; ++it)
    *(ushort4*)&xs[xrow + it * 8][xslot * 4] = f4bf(px[it]);
#pragma unroll
  for (int it = 0; it < 12; ++it)
    *(short8*)&ws[wrow + it * 16][wslot * 8] = pw[it];

  for (int c = 0; c < 8; ++c) {             // 8 chunks of 128 e
    __syncthreads();                        // staged chunk visible
    if (c < 7) {                            // dense prefetch of chunk c+1
      const int e0 = (c + 1) * 128;
#pragma unroll
      for (int it = 0; it < 4; ++it)
        px[it] = ((const float4*)(x + (row0 + xrow + it * 8) * E + e0))[xslot];
#pragma unroll
      for (int it = 0; it < 12; ++it)
        pw[it] = *(const short8*)(WT3 + (long)(wrow + it * 16) * E + e0 + wslot * 8);
    }
#pragma unroll
    for (int kh = 0; kh < 4; ++kh) {
      short8 a0 = *(const short8*)&xs[l15][kh * 32 + g * 8];
      short8 a1 = *(const short8*)&xs[16 + l15][kh * 32 + g * 8];
#pragma unroll
      for (int ct = 0; ct < 3; ++ct) {
        short8 b = *(const short8*)&ws[w * 48 + ct * 16 + l15][kh * 32 + g * 8];
        acc[0][ct] = __builtin_amdgcn_mfma_f32_16x16x32_bf16(a0, b, acc[0][ct], 0, 0, 0);
        acc[1][ct] = __builtin_amdgcn_mfma_f32_16x16x32_bf16(a1, b, acc[1][ct], 0, 0, 0);
      }
    }
    __syncthreads();                        // LDS reads done
    if (c < 7) {
#pragma unroll
      for (int it = 0; it < 4; ++it)
        *(ushort4*)&xs[xrow + it * 8][xslot * 4] = f4bf(px[it]);
#pragma unroll
      for (int it = 0; it < 12; ++it)
        *(short8*)&ws[wrow + it * 16][wslot * 8] = pw[it];
    }
  }

  const int bb = (int)(row0 >> 11);
  const int srow = (int)(row0 & 2047);
#pragma unroll
  for (int ct = 0; ct < 3; ++ct) {
    const int col = w * 48 + ct * 16 + l15;
    const int mm = col >> 6, ch = col & 63;
#pragma unroll
    for (int rt = 0; rt < 2; ++rt) {
      const int srl = rt * 16 + g * 4;
      if (mm == 0) {
#pragma unroll
        for (int r = 0; r < 4; ++r)
          q[(row0 + srl + r) * H + ch] = f2bf(acc[rt][ct][r] * SCALE);
      } else if (mm == 1) {
#pragma unroll
        for (int r = 0; r < 4; ++r)
          kk[(row0 + srl + r) * H + ch] = f2bf(acc[rt][ct][r]);
      } else {
        ushort4 v4 = make_ushort4(f2bf(acc[rt][ct][0]), f2bf(acc[rt][ct][1]),
                                  f2bf(acc[rt][ct][2]), f2bf(acc[rt][ct][3]));
        *(ushort4*)(vT + ((long)bb * H + ch) * S + srow + srl) = v4;
      }
    }
  }
}

// ---------- causal flash attention, S^T formulation, barrier-free loop ----
// S^T = K Q^T  =>  C col = l15 = q-row: per-lane scalar m/l/alpha, 2 shuffles
// per iteration. O^T = V^T P^T with V^T frags direct from vT. Wave =
// (qt 16-row tile, K-parity split); block = {qt=p, qt=127-p} x {split0,1};
// grid = 8 b x 64 p = 512. Single LDS merge of the two splits at the end.
__global__ __launch_bounds__(256, 2) void attn_kernel(
    const unsigned short* __restrict__ q, const unsigned short* __restrict__ k,
    const unsigned short* __restrict__ vT, float* __restrict__ out) {
  __shared__ unsigned short pl[4][16][72];  // per-wave P [qrow][key]
  __shared__ float Om[2][64][20];           // split-1 O^T [h][qrow]
  __shared__ float ms[2][16], ls[2][16];
  const int t = threadIdx.x;
  const int w = t >> 6, lane = t & 63, l15 = lane & 15, g = lane >> 4;
  const int b = blockIdx.x & 7, p = blockIdx.x >> 3;
  const int grp = w >> 1, sp = w & 1;       // qt-group, K-parity split
  const int qt = grp ? (127 - p) : p;       // p=0 (longest) dispatches first
  const int qrow0 = qt * 16;
  const int nt = (16 * qt + 79) >> 6;       // K64 tiles covering keys<=rows
  const unsigned short* kb = k + (long)b * S * H;
  const unsigned short* vb = vT + (long)b * H * S;
  const unsigned short* qp = q + ((long)b * S + qrow0 + l15) * H + g * 8;
  short8 bq0 = *(const short8*)qp;          // Q B-frags: n=l15=qrow, k=h
  short8 bq1 = *(const short8*)(qp + 32);

  f32x4 O[4];
#pragma unroll
  for (int c = 0; c < 4; ++c) O[c] = f32x4{0.f, 0.f, 0.f, 0.f};
  float m_ = -1e30f, l_ = 0.f;

  short8 ak[4][2];
  int kt = sp;
  if (kt < nt) {
#pragma unroll
    for (int c = 0; c < 4; ++c)
#pragma unroll
      for (int kh = 0; kh < 2; ++kh)
        ak[c][kh] = *(const short8*)(kb + (long)(kt * 64 + c * 16 + l15) * H + kh * 32 + g * 8);
  }

  for (; kt < nt; kt += 2) {
    // V^T A-frags issued early (consumed at the end of the iteration)
    short8 av[4][2];
#pragma unroll
    for (int c = 0; c < 4; ++c)
#pragma unroll
      for (int kh = 0; kh < 2; ++kh)
        av[c][kh] = *(const short8*)(vb + (long)(c * 16 + l15) * S + kt * 64 + kh * 32 + g * 8);
    // ---- S^T = K Q^T : D[m=key][n=qrow] ----
    f32x4 sc[4];
#pragma unroll
    for (int c = 0; c < 4; ++c) {
      sc[c] = f32x4{0.f, 0.f, 0.f, 0.f};
      sc[c] = __builtin_amdgcn_mfma_f32_16x16x32_bf16(ak[c][0], bq0, sc[c], 0, 0, 0);
      sc[c] = __builtin_amdgcn_mfma_f32_16x16x32_bf16(ak[c][1], bq1, sc[c], 0, 0, 0);
    }
    // prefetch K frags for kt+2
    if (kt + 2 < nt) {
#pragma unroll
      for (int c = 0; c < 4; ++c)
#pragma unroll
        for (int kh = 0; kh < 2; ++kh)
          ak[c][kh] = *(const short8*)(kb + (long)((kt + 2) * 64 + c * 16 + l15) * H + kh * 32 + g * 8);
    }
    if (kt == nt - 1) {                     // diagonal tile: mask key > qrow
#pragma unroll
      for (int c = 0; c < 4; ++c)
#pragma unroll
        for (int r = 0; r < 4; ++r)
          if (kt * 64 + c * 16 + g * 4 + r > qrow0 + l15) sc[c][r] = -1e30f;
    }
    // ---- per-lane softmax: 15 local ops + 2 shuffles each for max/sum ----
    float mx = -1e30f;
#pragma unroll
    for (int c = 0; c < 4; ++c)
#pragma unroll
      for (int r = 0; r < 4; ++r) mx = fmaxf(mx, sc[c][r]);
    mx = fmaxf(mx, __shfl_xor(mx, 16));
    mx = fmaxf(mx, __shfl_xor(mx, 32));
    float mn = fmaxf(m_, mx);
    float al = exp2f((m_ - mn) * LOG2E);
    float sum = 0.f;
#pragma unroll
    for (int c = 0; c < 4; ++c)
#pragma unroll
      for (int r = 0; r < 4; ++r) {
        float pe = exp2f((sc[c][r] - mn) * LOG2E);
        sc[c][r] = pe;
        sum += pe;
      }
    sum += __shfl_xor(sum, 16);
    sum += __shfl_xor(sum, 32);
    l_ = l_ * al + sum;
    m_ = mn;
    // ---- P^T -> per-wave LDS (4 ushort4 writes), O^T *= al (scalar) ----
#pragma unroll
    for (int c = 0; c < 4; ++c) {
      ushort4 p4 = make_ushort4(f2bf(sc[c][0]), f2bf(sc[c][1]),
                                f2bf(sc[c][2]), f2bf(sc[c][3]));
      *(ushort4*)&pl[w][l15][c * 16 + g * 4] = p4;
    }
#pragma unroll
    for (int c = 0; c < 4; ++c)
#pragma unroll
      for (int r = 0; r < 4; ++r) O[c][r] *= al;
    // ---- O^T += V^T P^T ----
    short8 bp0 = *(const short8*)&pl[w][l15][g * 8];
    short8 bp1 = *(const short8*)&pl[w][l15][32 + g * 8];
#pragma unroll
    for (int c = 0; c < 4; ++c) {
      O[c] = __builtin_amdgcn_mfma_f32_16x16x32_bf16(av[c][0], bp0, O[c], 0, 0, 0);
      O[c] = __builtin_amdgcn_mfma_f32_16x16x32_bf16(av[c][1], bp1, O[c], 0, 0, 0);
    }
  }

  // ---- merge the two K-parity splits of each qt ----
  if (sp == 1) {
#pragma unroll
    for (int c = 0; c < 4; ++c)
#pragma unroll
      for (int r = 0; r < 4; ++r)
        Om[grp][c * 16 + g * 4 + r][l15] = O[c][r];
    if (g == 0) { ms[grp][l15] = m_; ls[grp][l15] = l_; }
  }
  __syncthreads();
  if (sp == 0) {
    float m1 = ms[grp][l15], l1 = ls[grp][l15];
    float mstar = fmaxf(m_, m1);
    float f0 = exp2f((m_ - mstar) * LOG2E);
    float f1 = exp2f((m1 - mstar) * LOG2E);
    float inv = 1.0f / (l_ * f0 + l1 * f1);
    float* op = out + ((long)b * S + qrow0 + l15) * H;
#pragma unroll
    for (int c = 0; c < 4; ++c) {
      float4 o;
      o.x = (O[c][0] * f0 + Om[grp][c * 16 + g * 4 + 0][l15] * f1) * inv;
      o.y = (O[c][1] * f0 + Om[grp][c * 16 + g * 4 + 1][l15] * f1) * inv;
      o.z = (O[c][2] * f0 + Om[grp][c * 16 + g * 4 + 2][l15] * f1) * inv;
      o.w = (O[c][3] * f0 + Om[grp][c * 16 + g * 4 + 3][l15] * f1) * inv;
      *(float4*)(op + c * 16 + g * 4) = o;
    }
  }
}

extern "C" void kernel_launch(void* const* d_in, const int* in_sizes, int n_in,
                              void* d_out, int out_size, void* d_ws, size_t ws_size,
                              hipStream_t stream) {
  const float* x  = (const float*)d_in[0];
  const float* Wq = (const float*)d_in[1];
  const float* Wk = (const float*)d_in[2];
  const float* Wv = (const float*)d_in[3];
  float* outp = (float*)d_out;
  unsigned short* WT3 = (unsigned short*)d_ws;                       // 384 KB
  unsigned short* q  = (unsigned short*)((char*)d_ws + 512 * 1024);  // 2 MB each
  unsigned short* kk = q + (size_t)Bn * S * H;
  unsigned short* vT = kk + (size_t)Bn * S * H;
  wtrans_kernel<<<dim3(48), dim3(256), 0, stream>>>(Wq, Wk, Wv, WT3);
  qkv_kernel<<<dim3((Bn * S) / 32), dim3(256), 0, stream>>>(x, WT3, q, kk, vT);
  attn_kernel<<<dim3(Bn * 64), dim3(256), 0, stream>>>(q, kk, vT, outp);
}